// Round 7
// baseline (341.757 us; speedup 1.0000x reference)
//
#include <hip/hip_runtime.h>

#define NPTS 8192
#define NQ   2048
#define NBATCH 8
#define KNN  32
#define R2   0.04f   // fp32 cast of python 0.2**2
#define NQTOT (NBATCH * NQ)
#define PACK_F4 (NBATCH * NPTS)

// Pack pos (AoS, 12B stride) into float4(x,y,z,|p|^2). Norm with explicit
// round-to-nearest ops, no FMA contraction, reference order: (x*x+y*y)+z*z.
// Thread 0 also zeroes the work-stealing counter (re-done every launch).
__global__ __launch_bounds__(256)
void gg_prep(const float* __restrict__ pos, float4* __restrict__ pack,
             int* __restrict__ counter, int total) {
    int i = blockIdx.x * blockDim.x + threadIdx.x;
    if (i == 0) counter[0] = 0;
    if (i >= total) return;
    float x = pos[i * 3 + 0];
    float y = pos[i * 3 + 1];
    float z = pos[i * 3 + 2];
    float n = __fadd_rn(__fadd_rn(__fmul_rn(x, x), __fmul_rn(y, y)), __fmul_rn(z, z));
    pack[i] = make_float4(x, y, z, n);
}

// Branch-free test of 128 points [SUBI, SUBI+128): lane handles SUBI+lane and
// SUBI+64+lane. One col/first update per 128 pts. Distance matches reference
// op order exactly: s = (cn + pn) - 2*((cx*px + cy*py) + cz*pz).
#define TEST128(PA, PB, SUBI)                                                      \
    {                                                                              \
        float dotA = __fadd_rn(__fadd_rn(__fmul_rn(c.x, (PA).x),                   \
                                         __fmul_rn(c.y, (PA).y)),                  \
                               __fmul_rn(c.z, (PA).z));                            \
        float sA   = __fsub_rn(__fadd_rn(c.w, (PA).w), __fmul_rn(2.0f, dotA));     \
        float dotB = __fadd_rn(__fadd_rn(__fmul_rn(c.x, (PB).x),                   \
                                         __fmul_rn(c.y, (PB).y)),                  \
                               __fmul_rn(c.z, (PB).z));                            \
        float sB   = __fsub_rn(__fadd_rn(c.w, (PB).w), __fmul_rn(2.0f, dotB));     \
        bool kA = !(sA > R2), kB = !(sB > R2);                                     \
        unsigned long long mA = __ballot(kA), mB = __ballot(kB);                   \
        int pcA = (int)__popcll(mA);                                               \
        int pfA = (int)__builtin_amdgcn_mbcnt_hi((unsigned)(mA >> 32),             \
                      __builtin_amdgcn_mbcnt_lo((unsigned)mA, 0u));                \
        int pfB = (int)__builtin_amdgcn_mbcnt_hi((unsigned)(mB >> 32),             \
                      __builtin_amdgcn_mbcnt_lo((unsigned)mB, 0u));                \
        int slA = col + pfA;                                                       \
        int slB = col + pcA + pfB;                                                 \
        if (kA && slA < KNN) oq[slA] = (SUBI) + lane;                              \
        if (kB && slB < KNN) oq[slB] = (SUBI) + 64 + lane;                         \
        first = (col == 0 && mA) ? (SUBI) + (int)__builtin_ctzll(mA) : first;      \
        first = (col == 0 && !mA && mB)                                            \
                    ? (SUBI) + 64 + (int)__builtin_ctzll(mB) : first;              \
        col += pcA + (int)__popcll(mB);                                            \
    }

// Persistent waves, dynamic single-query work stealing. Each grabbed query:
// stream points 256/iteration (loads one full iteration ahead), two TEST128
// steps, wave-uniform early exit at 32 hits.
__global__ __launch_bounds__(256)
void gg_ballquery(const float4* __restrict__ pack,
                  const int* __restrict__ centroids,
                  int* __restrict__ out,
                  int* __restrict__ counter) {
    const int lane = threadIdx.x & 63;

    while (true) {
        int t;
        if (lane == 0) t = atomicAdd(counter, 1);
        t = __builtin_amdgcn_readfirstlane(t);
        if (t >= NQTOT) return;

        const int b = t >> 11;                       // batch
        const float4* __restrict__ pp = pack + b * NPTS;
        const float4 c = pp[centroids[t]];
        int* __restrict__ oq = out + t * KNN;

        int col = 0, first = NPTS;

        float4 r0 = pp[lane];
        float4 r1 = pp[lane + 64];
        float4 r2 = pp[lane + 128];
        float4 r3 = pp[lane + 192];

        #pragma unroll 1
        for (int base = 0; base < NPTS; base += 256) {
            float4 p0 = r0, p1 = r1, p2 = r2, p3 = r3;
            if (base + 256 < NPTS) {
                r0 = pp[base + 256 + lane];
                r1 = pp[base + 320 + lane];
                r2 = pp[base + 384 + lane];
                r3 = pp[base + 448 + lane];
            }
            TEST128(p0, p1, base);
            TEST128(p2, p3, base + 128);
            if (col >= KNN) break;                   // wave-uniform
        }

        // Pad tail slots [col, 32) with the first neighbor index.
        if (col < KNN && col + lane < KNN) oq[col + lane] = first;
    }
}

extern "C" void kernel_launch(void* const* d_in, const int* in_sizes, int n_in,
                              void* d_out, int out_size, void* d_ws, size_t ws_size,
                              hipStream_t stream) {
    const float* pos       = (const float*)d_in[0];   // (8, 8192, 3) f32
    const int*   centroids = (const int*)d_in[1];     // (8, 2048) int32
    int*         out       = (int*)d_out;             // (8, 2048, 32) int32

    float4* pack    = (float4*)d_ws;                  // 1 MiB
    int*    counter = (int*)((char*)d_ws + PACK_F4 * sizeof(float4));

    gg_prep<<<dim3((PACK_F4 + 255) / 256), dim3(256), 0, stream>>>(pos, pack, counter, PACK_F4);

    // 2048 blocks x 256 thr = 8192 persistent waves stealing 16384 queries.
    gg_ballquery<<<dim3(2048), dim3(256), 0, stream>>>(pack, centroids, out, counter);
}

// Round 8
// 83.718 us; speedup vs baseline: 4.0822x; 4.0822x over previous
//
#include <hip/hip_runtime.h>

#define NPTS 8192
#define NQ   2048
#define NBATCH 8
#define KNN  32
#define R2   0.04f   // fp32 cast of python 0.2**2
#define NQTOT (NBATCH * NQ)
#define PACK_F4 (NBATCH * NPTS)

// Pack pos (AoS, 12B stride) into float4(x,y,z,|p|^2). Norm with explicit
// round-to-nearest ops, no FMA contraction, reference order: (x*x+y*y)+z*z.
__global__ __launch_bounds__(256)
void gg_prep(const float* __restrict__ pos, float4* __restrict__ pack, int total) {
    int i = blockIdx.x * blockDim.x + threadIdx.x;
    if (i >= total) return;
    float x = pos[i * 3 + 0];
    float y = pos[i * 3 + 1];
    float z = pos[i * 3 + 2];
    float n = __fadd_rn(__fadd_rn(__fmul_rn(x, x), __fmul_rn(y, y)), __fmul_rn(z, z));
    pack[i] = make_float4(x, y, z, n);
}

// Branch-free test of 128 points [SUBI, SUBI+128) for one query: lane handles
// SUBI+lane and SUBI+64+lane. One col/first update per 128 pts. Distance
// matches reference op order exactly:
//   s = (cn + pn) - 2*((cx*px + cy*py) + cz*pz)
#define TEST128Q(C, COL, FIRST, OQ, PA, PB, SUBI)                                  \
    {                                                                              \
        float dotA = __fadd_rn(__fadd_rn(__fmul_rn((C).x, (PA).x),                 \
                                         __fmul_rn((C).y, (PA).y)),                \
                               __fmul_rn((C).z, (PA).z));                          \
        float sA   = __fsub_rn(__fadd_rn((C).w, (PA).w), __fmul_rn(2.0f, dotA));   \
        float dotB = __fadd_rn(__fadd_rn(__fmul_rn((C).x, (PB).x),                 \
                                         __fmul_rn((C).y, (PB).y)),                \
                               __fmul_rn((C).z, (PB).z));                          \
        float sB   = __fsub_rn(__fadd_rn((C).w, (PB).w), __fmul_rn(2.0f, dotB));   \
        bool kA = !(sA > R2), kB = !(sB > R2);                                     \
        unsigned long long mA = __ballot(kA), mB = __ballot(kB);                   \
        int pcA = (int)__popcll(mA);                                               \
        int pfA = (int)__builtin_amdgcn_mbcnt_hi((unsigned)(mA >> 32),             \
                      __builtin_amdgcn_mbcnt_lo((unsigned)mA, 0u));                \
        int pfB = (int)__builtin_amdgcn_mbcnt_hi((unsigned)(mB >> 32),             \
                      __builtin_amdgcn_mbcnt_lo((unsigned)mB, 0u));                \
        int slA = (COL) + pfA;                                                     \
        int slB = (COL) + pcA + pfB;                                               \
        if (kA && slA < KNN) (OQ)[slA] = (SUBI) + lane;                            \
        if (kB && slB < KNN) (OQ)[slB] = (SUBI) + 64 + lane;                       \
        (FIRST) = ((COL) == 0 && mA) ? (SUBI) + (int)__builtin_ctzll(mA) : (FIRST);\
        (FIRST) = ((COL) == 0 && !mA && mB)                                        \
                      ? (SUBI) + 64 + (int)__builtin_ctzll(mB) : (FIRST);          \
        (COL) += pcA + (int)__popcll(mB);                                          \
    }

// Static: one wave per TWO adjacent queries (same batch). 256 pts/iteration,
// loads issued one iteration ahead; per-query wave-uniform guards; early exit
// when both queries have 32 hits. 4 waves/block, 2048 blocks -> 8192 waves
// (8/SIMD full occupancy). No atomics.
__global__ __launch_bounds__(256)
void gg_ballquery(const float4* __restrict__ pack,
                  const int* __restrict__ centroids,
                  int* __restrict__ out) {
    const int wid  = threadIdx.x >> 6;
    const int lane = threadIdx.x & 63;
    const int w    = blockIdx.x * 4 + wid;          // wave id: 0 .. 8191
    const int q0   = w * 2;                         // two consecutive queries
    const int b    = q0 >> 11;                      // batch

    const float4* __restrict__ pp = pack + b * NPTS;

    const float4 cA = pp[centroids[q0]];
    const float4 cB = pp[centroids[q0 + 1]];

    int* __restrict__ oA = out + q0 * KNN;
    int* __restrict__ oB = oA + KNN;

    int colA = 0, colB = 0;
    int fA = NPTS, fB = NPTS;

    // Prefetch iteration 0 (points [0, 256))
    float4 r0 = pp[lane];
    float4 r1 = pp[lane + 64];
    float4 r2 = pp[lane + 128];
    float4 r3 = pp[lane + 192];

    #pragma unroll 1
    for (int base = 0; base < NPTS; base += 256) {
        float4 p0 = r0, p1 = r1, p2 = r2, p3 = r3;
        if (base + 256 < NPTS) {                    // prefetch next 256 points
            r0 = pp[base + 256 + lane];
            r1 = pp[base + 320 + lane];
            r2 = pp[base + 384 + lane];
            r3 = pp[base + 448 + lane];
        }

        if (colA < KNN) {
            TEST128Q(cA, colA, fA, oA, p0, p1, base);
            TEST128Q(cA, colA, fA, oA, p2, p3, base + 128);
        }
        if (colB < KNN) {
            TEST128Q(cB, colB, fB, oB, p0, p1, base);
            TEST128Q(cB, colB, fB, oB, p2, p3, base + 128);
        }
        if (colA >= KNN && colB >= KNN) break;      // wave-uniform early exit
    }

    // Pad tail slots [col, 32) with the first neighbor index.
    if (colA < KNN && colA + lane < KNN) oA[colA + lane] = fA;
    if (colB < KNN && colB + lane < KNN) oB[colB + lane] = fB;
}

extern "C" void kernel_launch(void* const* d_in, const int* in_sizes, int n_in,
                              void* d_out, int out_size, void* d_ws, size_t ws_size,
                              hipStream_t stream) {
    const float* pos       = (const float*)d_in[0];   // (8, 8192, 3) f32
    const int*   centroids = (const int*)d_in[1];     // (8, 2048) int32
    int*         out       = (int*)d_out;             // (8, 2048, 32) int32

    float4* pack = (float4*)d_ws;                     // 1 MiB scratch

    gg_prep<<<dim3((PACK_F4 + 255) / 256), dim3(256), 0, stream>>>(pos, pack, PACK_F4);

    const int nw = NQTOT / 2;                         // 8192 waves, 4 per block
    gg_ballquery<<<dim3(nw / 4), dim3(256), 0, stream>>>(pack, centroids, out);
}